// Round 4
// baseline (361.510 us; speedup 1.0000x reference)
//
#include <hip/hip_runtime.h>

#define IN_DIM 128
#define HID    64
#define OUTD   32

#define BSHIFT 9
#define BNODES 512                 // 1 << BSHIFT
#define NB     196                 // ceil(100000 / 512)
#define CHUNK  4096                // edges per k_bscatter block

// ================= Pass A: coarse bucket counts =================

__launch_bounds__(256)
__global__ void k_bcount(const int* __restrict__ dst, int* __restrict__ bucketCnt, int E) {
    __shared__ int h[NB];
    int t = threadIdx.x;
    for (int i = t; i < NB; i += 256) h[i] = 0;
    __syncthreads();
    int stride = gridDim.x * blockDim.x;
    for (int e = blockIdx.x * blockDim.x + t; e < E; e += stride)
        atomicAdd(&h[__builtin_nontemporal_load(dst + e) >> BSHIFT], 1);
    __syncthreads();
    for (int i = t; i < NB; i += 256)
        if (h[i]) atomicAdd(&bucketCnt[i], h[i]);
}

// ================= scan bucket counts -> bases & cursors =================

__global__ void k_bscan(const int* __restrict__ bucketCnt, int* __restrict__ bucketBase,
                        int* __restrict__ bucketCursor, int* __restrict__ rs, int N, int E) {
    __shared__ int sd[256];
    int t = threadIdx.x;
    int v = (t < NB) ? bucketCnt[t] : 0;
    sd[t] = v;
    __syncthreads();
    for (int off = 1; off < 256; off <<= 1) {
        int u = (t >= off) ? sd[t - off] : 0;
        __syncthreads();
        sd[t] += u;
        __syncthreads();
    }
    int excl = sd[t] - v;
    if (t < NB) { bucketBase[t] = excl; bucketCursor[t] = excl; }
    if (t == 0) { bucketBase[NB] = E; rs[N] = E; }
}

// ================= Pass B: scatter edges into buckets (packed src<<9 | dst_local) =================

__launch_bounds__(256)
__global__ void k_bscatter(const int* __restrict__ src, const int* __restrict__ dst,
                           int* __restrict__ bucketCursor, int* __restrict__ ebuf, int E) {
    __shared__ int h[NB];
    __shared__ int lbase[NB];
    __shared__ int lcur[NB];
    int t = threadIdx.x;
    int base = blockIdx.x * CHUNK;
    int end = min(base + CHUNK, E);
    for (int i = t; i < NB; i += 256) { h[i] = 0; lcur[i] = 0; }
    __syncthreads();
    for (int i = base + t; i < end; i += 256)
        atomicAdd(&h[dst[i] >> BSHIFT], 1);
    __syncthreads();
    for (int i = t; i < NB; i += 256)
        lbase[i] = h[i] ? atomicAdd(&bucketCursor[i], h[i]) : 0;
    __syncthreads();
    for (int i = base + t; i < end; i += 256) {
        int d = dst[i];
        int b = d >> BSHIFT;
        int off = atomicAdd(&lcur[b], 1);
        ebuf[lbase[b] + off] = (src[i] << BSHIFT) | (d & (BNODES - 1));
    }
}

// ================= Pass C: per-bucket fine CSR build + rs + dinv =================

__launch_bounds__(256)
__global__ void k_bfinal(const int* __restrict__ ebuf, const int* __restrict__ bucketBase,
                         int* __restrict__ rs, float* __restrict__ dinv,
                         int* __restrict__ csr, int N) {
    __shared__ int hist[BNODES];
    __shared__ int rsl[BNODES];
    __shared__ int ssum[256];
    int t = threadIdx.x;
    int b = blockIdx.x;
    int nodeBase = b << BSHIFT;
    int ebase = bucketBase[b], eend = bucketBase[b + 1];

    hist[t] = 0; hist[t + 256] = 0;
    __syncthreads();
    for (int i = ebase + t; i < eend; i += 256)
        atomicAdd(&hist[__builtin_nontemporal_load(ebuf + i) & (BNODES - 1)], 1);
    __syncthreads();

    int h0 = hist[2 * t], h1 = hist[2 * t + 1];
    ssum[t] = h0 + h1;
    __syncthreads();
    for (int off = 1; off < 256; off <<= 1) {
        int u = (t >= off) ? ssum[t - off] : 0;
        __syncthreads();
        ssum[t] += u;
        __syncthreads();
    }
    int excl = ssum[t] - h0 - h1;
    rsl[2 * t]     = excl;
    rsl[2 * t + 1] = excl + h0;

    int n0 = nodeBase + 2 * t, n1 = n0 + 1;
    if (n0 < N) { rs[n0] = ebase + excl;      dinv[n0] = rsqrtf((float)h0 + 1.0f); }
    if (n1 < N) { rs[n1] = ebase + excl + h0; dinv[n1] = rsqrtf((float)h1 + 1.0f); }

    hist[2 * t] = 0; hist[2 * t + 1] = 0;   // reuse as per-node cursors
    __syncthreads();

    for (int i = ebase + t; i < eend; i += 256) {
        int p = ebuf[i];
        int l = p & (BNODES - 1);
        int off = atomicAdd(&hist[l], 1);
        csr[ebase + rsl[l] + off] = ((unsigned)p) >> BSHIFT;
    }
}

// ================= layer 1 GEMM: hs1_c[c][node][8] = ((x @ W1) * dinv)[cols 8c..8c+7] =================

__launch_bounds__(256)
__global__ void k_gemm1(const float* __restrict__ x, const float* __restrict__ W1,
                        const float* __restrict__ dinv, float* __restrict__ hs1, int N) {
    __shared__ float Ws[IN_DIM * HID];     // [k][f]
    __shared__ float xs[32 * 132];
    const int t = threadIdx.x;
    const int base = blockIdx.x * 32;
    const size_t N8 = (size_t)N * 8;

    {
        const float4* s4 = (const float4*)W1;
        float4* d4 = (float4*)Ws;
        for (int i = t; i < IN_DIM * HID / 4; i += 256) d4[i] = s4[i];
    }
    {
        const float4* s4 = (const float4*)(x + (size_t)base * IN_DIM);
        for (int i = t; i < 32 * IN_DIM / 4; i += 256) {
            float4 v = s4[i];
            int node = i >> 5;
            int k4   = i & 31;
            *(float4*)&xs[node * 132 + k4 * 4] = v;
        }
    }
    __syncthreads();

    const int fq = t & 15;
    const int nl = t >> 4;
    const float4* Wf4 = (const float4*)Ws;

    float4 a0 = {0,0,0,0}, a1 = {0,0,0,0};
    #pragma unroll 8
    for (int k = 0; k < IN_DIM; ++k) {
        float4 w = Wf4[k * 16 + fq];
        float x0 = xs[nl * 132 + k];
        float x1 = xs[(nl + 16) * 132 + k];
        a0.x += x0 * w.x; a0.y += x0 * w.y; a0.z += x0 * w.z; a0.w += x0 * w.w;
        a1.x += x1 * w.x; a1.y += x1 * w.y; a1.z += x1 * w.z; a1.w += x1 * w.w;
    }
    int n0 = base + nl, n1 = base + nl + 16;
    float d0 = dinv[n0], d1 = dinv[n1];
    a0.x *= d0; a0.y *= d0; a0.z *= d0; a0.w *= d0;
    a1.x *= d1; a1.y *= d1; a1.z *= d1; a1.w *= d1;
    const int c = fq >> 1, half = (fq & 1) * 4;
    *(float4*)(hs1 + (size_t)c * N8 + (size_t)n0 * 8 + half) = a0;
    *(float4*)(hs1 + (size_t)c * N8 + (size_t)n1 * 8 + half) = a1;
}

// ================= chunked CSR aggregation, layer 1 =================
// chunk = blockIdx.x & 7 -> pinned to one XCD by round-robin dispatch; 2 lanes/node.

__launch_bounds__(256)
__global__ void k_agg1(const float* __restrict__ hs, const int* __restrict__ rs,
                       const int* __restrict__ csr, float* __restrict__ agg, int N) {
    const int c = blockIdx.x & 7;
    const int node = (blockIdx.x >> 3) * 128 + (threadIdx.x >> 1);
    if (node >= N) return;
    const int lane = threadIdx.x & 1;
    const size_t N8 = (size_t)N * 8;
    const float4* h4 = (const float4*)(hs + (size_t)c * N8);

    float4 a = h4[node * 2 + lane];   // self-loop
    float4 b = {0,0,0,0};
    int i = rs[node], end = rs[node + 1];
    for (; i + 2 <= end; i += 2) {
        int s0 = __builtin_nontemporal_load(csr + i);
        int s1 = __builtin_nontemporal_load(csr + i + 1);
        float4 v0 = h4[s0 * 2 + lane];
        float4 v1 = h4[s1 * 2 + lane];
        a.x += v0.x; a.y += v0.y; a.z += v0.z; a.w += v0.w;
        b.x += v1.x; b.y += v1.y; b.z += v1.z; b.w += v1.w;
    }
    if (i < end) {
        int s0 = __builtin_nontemporal_load(csr + i);
        float4 v0 = h4[s0 * 2 + lane];
        a.x += v0.x; a.y += v0.y; a.z += v0.z; a.w += v0.w;
    }
    a.x += b.x; a.y += b.y; a.z += b.z; a.w += b.w;
    ((float4*)(agg + (size_t)c * N8))[node * 2 + lane] = a;
}

// ================= layer 2 GEMM: reads agg chunk-major; hs2_c[c][node][8] chunk-major =================

__launch_bounds__(256)
__global__ void k_gemm2(const float* __restrict__ agg1, const float* __restrict__ W2,
                        const float* __restrict__ b1, const float* __restrict__ dinv,
                        float* __restrict__ hs2, int N) {
    __shared__ float Ws[HID * OUTD];
    __shared__ float L1s[32 * 68];
    const int t = threadIdx.x;
    const int base = blockIdx.x * 32;
    const size_t N8 = (size_t)N * 8;

    for (int i = t; i < HID * OUTD / 4; i += 256)
        ((float4*)Ws)[i] = ((const float4*)W2)[i];

    for (int e = t; e < 32 * HID; e += 256) {
        int n_l = e >> 6, k = e & 63;
        int gn = base + n_l;
        float v = dinv[gn] * agg1[(size_t)(k >> 3) * N8 + (size_t)gn * 8 + (k & 7)] + b1[k];
        L1s[n_l * 68 + k] = fmaxf(v, 0.0f);
    }
    __syncthreads();

    const int fq = t & 7;
    const int nl = t >> 3;
    float4 a = {0,0,0,0};
    #pragma unroll 8
    for (int k = 0; k < HID; ++k) {
        float4 w = ((const float4*)Ws)[k * 8 + fq];
        float xv = L1s[nl * 68 + k];
        a.x += xv * w.x; a.y += xv * w.y; a.z += xv * w.z; a.w += xv * w.w;
    }
    int n = base + nl;
    float d = dinv[n];
    a.x *= d; a.y *= d; a.z *= d; a.w *= d;
    const int c = fq >> 1, half = (fq & 1) * 4;
    *(float4*)(hs2 + (size_t)c * N8 + (size_t)n * 8 + half) = a;
}

// ================= chunked CSR aggregation, layer 2 + fused epilogue =================
// chunk = blockIdx.x & 3; out written row-major [N][32].

__launch_bounds__(256)
__global__ void k_agg2(const float* __restrict__ hs, const int* __restrict__ rs,
                       const int* __restrict__ csr, const float* __restrict__ dinv,
                       const float* __restrict__ b2, float* __restrict__ out, int N) {
    const int c = blockIdx.x & 3;
    const int node = (blockIdx.x >> 2) * 128 + (threadIdx.x >> 1);
    if (node >= N) return;
    const int lane = threadIdx.x & 1;
    const size_t N8 = (size_t)N * 8;
    const float4* h4 = (const float4*)(hs + (size_t)c * N8);

    float4 a = h4[node * 2 + lane];   // self-loop
    float4 b = {0,0,0,0};
    int i = rs[node], end = rs[node + 1];
    for (; i + 2 <= end; i += 2) {
        int s0 = __builtin_nontemporal_load(csr + i);
        int s1 = __builtin_nontemporal_load(csr + i + 1);
        float4 v0 = h4[s0 * 2 + lane];
        float4 v1 = h4[s1 * 2 + lane];
        a.x += v0.x; a.y += v0.y; a.z += v0.z; a.w += v0.w;
        b.x += v1.x; b.y += v1.y; b.z += v1.z; b.w += v1.w;
    }
    if (i < end) {
        int s0 = __builtin_nontemporal_load(csr + i);
        float4 v0 = h4[s0 * 2 + lane];
        a.x += v0.x; a.y += v0.y; a.z += v0.z; a.w += v0.w;
    }
    float dn = dinv[node];
    float4 bb = ((const float4*)b2)[c * 2 + lane];
    float4 o;
    o.x = fmaxf((a.x + b.x) * dn + bb.x, 0.0f);
    o.y = fmaxf((a.y + b.y) * dn + bb.y, 0.0f);
    o.z = fmaxf((a.z + b.z) * dn + bb.z, 0.0f);
    o.w = fmaxf((a.w + b.w) * dn + bb.w, 0.0f);
    ((float4*)out)[(size_t)node * 8 + c * 2 + lane] = o;
}

// ================= launch =================

extern "C" void kernel_launch(void* const* d_in, const int* in_sizes, int n_in,
                              void* d_out, int out_size, void* d_ws, size_t ws_size,
                              hipStream_t stream) {
    const float* x  = (const float*)d_in[0];
    const int*   ei = (const int*)  d_in[1];
    const float* W1 = (const float*)d_in[2];
    const float* b1 = (const float*)d_in[3];
    const float* W2 = (const float*)d_in[4];
    const float* b2 = (const float*)d_in[5];

    const int N = in_sizes[0] / IN_DIM;   // 100000
    const int E = in_sizes[1] / 2;        // 1600000
    const int* srcI = ei;
    const int* dstI = ei + E;
    float* out = (float*)d_out;

    float* dinv         = (float*)d_ws;                       // 131072 slot
    int*   rs           = (int*)d_ws + 131072;                // N+1 (131072 slot)
    int*   bucketCnt    = rs + 131072;                        // 256
    int*   bucketBase   = bucketCnt + 256;                    // 256 (NB+1)
    int*   bucketCursor = bucketBase + 256;                   // 256
    int*   ebuf         = bucketCursor + 256;                 // E packed words
    int*   csr          = ebuf + E;                           // E
    float* bufA         = (float*)(csr + E);                  // N*HID (hs1_c, later hs2_c)
    float* bufB         = bufA + (size_t)N * HID;             // N*HID (agg1_c)

    hipMemsetAsync(bucketCnt, 0, NB * sizeof(int), stream);
    k_bcount  <<<256, 256, 0, stream>>>(dstI, bucketCnt, E);
    k_bscan   <<<1, 256, 0, stream>>>(bucketCnt, bucketBase, bucketCursor, rs, N, E);
    k_bscatter<<<(E + CHUNK - 1) / CHUNK, 256, 0, stream>>>(srcI, dstI, bucketCursor, ebuf, E);
    k_bfinal  <<<NB, 256, 0, stream>>>(ebuf, bucketBase, rs, dinv, csr, N);

    const int nodeBlocks = (N + 127) / 128;   // 782
    k_gemm1<<<(N + 31) / 32, 256, 0, stream>>>(x, W1, dinv, bufA, N);
    k_agg1 <<<nodeBlocks * 8, 256, 0, stream>>>(bufA, rs, csr, bufB, N);
    k_gemm2<<<(N + 31) / 32, 256, 0, stream>>>(bufB, W2, b1, dinv, bufA, N);
    k_agg2 <<<nodeBlocks * 4, 256, 0, stream>>>(bufA, rs, csr, dinv, b2, out, N);
}

// Round 5
// 197.644 us; speedup vs baseline: 1.8291x; 1.8291x over previous
//
#include <hip/hip_runtime.h>

#define IN_DIM 128
#define HID    64
#define OUTD   32

#define BSHIFT 9
#define BNODES 512                 // 1 << BSHIFT
#define NB     196                 // ceil(100000 / 512)
#define CHUNK  4096                // edges per k_bscatter block

// ---- bf16 helpers (RNE pack, shift-unpack) ----

__device__ __forceinline__ unsigned bfp2(float x, float y) {
    unsigned a = __float_as_uint(x); a = a + 0x7FFF + ((a >> 16) & 1);
    unsigned b = __float_as_uint(y); b = b + 0x7FFF + ((b >> 16) & 1);
    return (a >> 16) | (b & 0xFFFF0000u);
}

__device__ __forceinline__ void acc8(float* f, uint4 q) {
    f[0] += __uint_as_float(q.x << 16); f[1] += __uint_as_float(q.x & 0xFFFF0000u);
    f[2] += __uint_as_float(q.y << 16); f[3] += __uint_as_float(q.y & 0xFFFF0000u);
    f[4] += __uint_as_float(q.z << 16); f[5] += __uint_as_float(q.z & 0xFFFF0000u);
    f[6] += __uint_as_float(q.w << 16); f[7] += __uint_as_float(q.w & 0xFFFF0000u);
}

// ================= Pass A: coarse bucket counts =================

__launch_bounds__(256)
__global__ void k_bcount(const int* __restrict__ dst, int* __restrict__ bucketCnt, int E) {
    __shared__ int h[NB];
    int t = threadIdx.x;
    for (int i = t; i < NB; i += 256) h[i] = 0;
    __syncthreads();
    int stride = gridDim.x * blockDim.x;
    for (int e = blockIdx.x * blockDim.x + t; e < E; e += stride)
        atomicAdd(&h[__builtin_nontemporal_load(dst + e) >> BSHIFT], 1);
    __syncthreads();
    for (int i = t; i < NB; i += 256)
        if (h[i]) atomicAdd(&bucketCnt[i], h[i]);
}

// ================= scan bucket counts -> bases & cursors =================

__global__ void k_bscan(const int* __restrict__ bucketCnt, int* __restrict__ bucketBase,
                        int* __restrict__ bucketCursor, int* __restrict__ rs, int N, int E) {
    __shared__ int sd[256];
    int t = threadIdx.x;
    int v = (t < NB) ? bucketCnt[t] : 0;
    sd[t] = v;
    __syncthreads();
    for (int off = 1; off < 256; off <<= 1) {
        int u = (t >= off) ? sd[t - off] : 0;
        __syncthreads();
        sd[t] += u;
        __syncthreads();
    }
    int excl = sd[t] - v;
    if (t < NB) { bucketBase[t] = excl; bucketCursor[t] = excl; }
    if (t == 0) { bucketBase[NB] = E; rs[N] = E; }
}

// ================= Pass B: scatter edges into buckets (packed src<<9 | dst_local) =================

__launch_bounds__(256)
__global__ void k_bscatter(const int* __restrict__ src, const int* __restrict__ dst,
                           int* __restrict__ bucketCursor, int* __restrict__ ebuf, int E) {
    __shared__ int h[NB];
    __shared__ int lbase[NB];
    __shared__ int lcur[NB];
    int t = threadIdx.x;
    int base = blockIdx.x * CHUNK;
    int end = min(base + CHUNK, E);
    for (int i = t; i < NB; i += 256) { h[i] = 0; lcur[i] = 0; }
    __syncthreads();
    for (int i = base + t; i < end; i += 256)
        atomicAdd(&h[dst[i] >> BSHIFT], 1);
    __syncthreads();
    for (int i = t; i < NB; i += 256)
        lbase[i] = h[i] ? atomicAdd(&bucketCursor[i], h[i]) : 0;
    __syncthreads();
    for (int i = base + t; i < end; i += 256) {
        int d = dst[i];
        int b = d >> BSHIFT;
        int off = atomicAdd(&lcur[b], 1);
        ebuf[lbase[b] + off] = (src[i] << BSHIFT) | (d & (BNODES - 1));
    }
}

// ================= Pass C: per-bucket fine CSR build + rs + dinv =================

__launch_bounds__(256)
__global__ void k_bfinal(const int* __restrict__ ebuf, const int* __restrict__ bucketBase,
                         int* __restrict__ rs, float* __restrict__ dinv,
                         int* __restrict__ csr, int N) {
    __shared__ int hist[BNODES];
    __shared__ int rsl[BNODES];
    __shared__ int ssum[256];
    int t = threadIdx.x;
    int b = blockIdx.x;
    int nodeBase = b << BSHIFT;
    int ebase = bucketBase[b], eend = bucketBase[b + 1];

    hist[t] = 0; hist[t + 256] = 0;
    __syncthreads();
    for (int i = ebase + t; i < eend; i += 256)
        atomicAdd(&hist[__builtin_nontemporal_load(ebuf + i) & (BNODES - 1)], 1);
    __syncthreads();

    int h0 = hist[2 * t], h1 = hist[2 * t + 1];
    ssum[t] = h0 + h1;
    __syncthreads();
    for (int off = 1; off < 256; off <<= 1) {
        int u = (t >= off) ? ssum[t - off] : 0;
        __syncthreads();
        ssum[t] += u;
        __syncthreads();
    }
    int excl = ssum[t] - h0 - h1;
    rsl[2 * t]     = excl;
    rsl[2 * t + 1] = excl + h0;

    int n0 = nodeBase + 2 * t, n1 = n0 + 1;
    if (n0 < N) { rs[n0] = ebase + excl;      dinv[n0] = rsqrtf((float)h0 + 1.0f); }
    if (n1 < N) { rs[n1] = ebase + excl + h0; dinv[n1] = rsqrtf((float)h1 + 1.0f); }

    hist[2 * t] = 0; hist[2 * t + 1] = 0;   // reuse as per-node cursors
    __syncthreads();

    for (int i = ebase + t; i < eend; i += 256) {
        int p = ebuf[i];
        int l = p & (BNODES - 1);
        int off = atomicAdd(&hist[l], 1);
        csr[ebase + rsl[l] + off] = ((unsigned)p) >> BSHIFT;
    }
}

// ================= layer 1 GEMM: hs1 (bf16 [N][64]) = (x @ W1) * dinv[row] =================

__launch_bounds__(256)
__global__ void k_gemm1(const float* __restrict__ x, const float* __restrict__ W1,
                        const float* __restrict__ dinv, uint2* __restrict__ hs1b) {
    __shared__ float Ws[IN_DIM * HID];     // [k][f]
    __shared__ float xs[32 * 132];
    const int t = threadIdx.x;
    const int base = blockIdx.x * 32;

    {
        const float4* s4 = (const float4*)W1;
        float4* d4 = (float4*)Ws;
        for (int i = t; i < IN_DIM * HID / 4; i += 256) d4[i] = s4[i];
    }
    {
        const float4* s4 = (const float4*)(x + (size_t)base * IN_DIM);
        for (int i = t; i < 32 * IN_DIM / 4; i += 256) {
            float4 v = s4[i];
            int node = i >> 5;
            int k4   = i & 31;
            *(float4*)&xs[node * 132 + k4 * 4] = v;
        }
    }
    __syncthreads();

    const int fq = t & 15;
    const int nl = t >> 4;
    const float4* Wf4 = (const float4*)Ws;

    float4 a0 = {0,0,0,0}, a1 = {0,0,0,0};
    #pragma unroll 8
    for (int k = 0; k < IN_DIM; ++k) {
        float4 w = Wf4[k * 16 + fq];
        float x0 = xs[nl * 132 + k];
        float x1 = xs[(nl + 16) * 132 + k];
        a0.x += x0 * w.x; a0.y += x0 * w.y; a0.z += x0 * w.z; a0.w += x0 * w.w;
        a1.x += x1 * w.x; a1.y += x1 * w.y; a1.z += x1 * w.z; a1.w += x1 * w.w;
    }
    int n0 = base + nl, n1 = base + nl + 16;
    float d0 = dinv[n0], d1 = dinv[n1];
    a0.x *= d0; a0.y *= d0; a0.z *= d0; a0.w *= d0;
    a1.x *= d1; a1.y *= d1; a1.z *= d1; a1.w *= d1;
    hs1b[(size_t)n0 * 16 + fq] = make_uint2(bfp2(a0.x, a0.y), bfp2(a0.z, a0.w));
    hs1b[(size_t)n1 * 16 + fq] = make_uint2(bfp2(a1.x, a1.y), bfp2(a1.z, a1.w));
}

// ================= CSR aggregation, layer 1: bf16 gather, fp32 accum =================
// 8 lanes/node, each lane one uint4 (8 bf16 = 16B); row = 128B.

__launch_bounds__(256)
__global__ void k_agg1(const uint4* __restrict__ hs, const int* __restrict__ rs,
                       const int* __restrict__ csr, float* __restrict__ agg, int N) {
    int tid = blockIdx.x * 256 + threadIdx.x;
    int node = tid >> 3;
    if (node >= N) return;
    int lane = tid & 7;

    float fa[8] = {0,0,0,0,0,0,0,0};
    float fb[8] = {0,0,0,0,0,0,0,0};
    acc8(fa, hs[(size_t)node * 8 + lane]);   // self-loop
    int i = rs[node], end = rs[node + 1];
    for (; i + 2 <= end; i += 2) {
        int s0 = __builtin_nontemporal_load(csr + i);
        int s1 = __builtin_nontemporal_load(csr + i + 1);
        acc8(fa, hs[(size_t)s0 * 8 + lane]);
        acc8(fb, hs[(size_t)s1 * 8 + lane]);
    }
    if (i < end) {
        int s0 = __builtin_nontemporal_load(csr + i);
        acc8(fa, hs[(size_t)s0 * 8 + lane]);
    }
    #pragma unroll
    for (int j = 0; j < 8; ++j) fa[j] += fb[j];
    float4* o = (float4*)(agg + (size_t)node * HID + lane * 8);
    o[0] = make_float4(fa[0], fa[1], fa[2], fa[3]);
    o[1] = make_float4(fa[4], fa[5], fa[6], fa[7]);
}

// ================= layer 2 GEMM: L1 = relu(dinv*agg1 + b1); hs2 (bf16 [N][32]) = (L1 @ W2) * dinv =================

__launch_bounds__(256)
__global__ void k_gemm2(const float* __restrict__ agg1, const float* __restrict__ W2,
                        const float* __restrict__ b1, const float* __restrict__ dinv,
                        uint2* __restrict__ hs2b) {
    __shared__ float Ws[HID * OUTD];
    __shared__ float L1s[32 * 68];
    const int t = threadIdx.x;
    const int base = blockIdx.x * 32;

    for (int i = t; i < HID * OUTD / 4; i += 256)
        ((float4*)Ws)[i] = ((const float4*)W2)[i];

    for (int e = t; e < 32 * HID; e += 256) {
        int n_l = e >> 6, k = e & 63;
        int gn = base + n_l;
        float v = dinv[gn] * agg1[(size_t)gn * HID + k] + b1[k];
        L1s[n_l * 68 + k] = fmaxf(v, 0.0f);
    }
    __syncthreads();

    const int fq = t & 7;
    const int nl = t >> 3;
    float4 a = {0,0,0,0};
    #pragma unroll 8
    for (int k = 0; k < HID; ++k) {
        float4 w = ((const float4*)Ws)[k * 8 + fq];
        float xv = L1s[nl * 68 + k];
        a.x += xv * w.x; a.y += xv * w.y; a.z += xv * w.z; a.w += xv * w.w;
    }
    int n = base + nl;
    float d = dinv[n];
    a.x *= d; a.y *= d; a.z *= d; a.w *= d;
    hs2b[(size_t)n * 8 + fq] = make_uint2(bfp2(a.x, a.y), bfp2(a.z, a.w));
}

// ================= CSR aggregation, layer 2 + fused epilogue: bf16 gather =================
// 4 lanes/node, each lane one uint4 (8 bf16); row = 64B. out fp32 [N][32].

__launch_bounds__(256)
__global__ void k_agg2(const uint4* __restrict__ hs, const int* __restrict__ rs,
                       const int* __restrict__ csr, const float* __restrict__ dinv,
                       const float* __restrict__ b2, float* __restrict__ out, int N) {
    int tid = blockIdx.x * 256 + threadIdx.x;
    int node = tid >> 2;
    if (node >= N) return;
    int lane = tid & 3;

    float fa[8] = {0,0,0,0,0,0,0,0};
    float fb[8] = {0,0,0,0,0,0,0,0};
    acc8(fa, hs[(size_t)node * 4 + lane]);   // self-loop
    int i = rs[node], end = rs[node + 1];
    for (; i + 2 <= end; i += 2) {
        int s0 = __builtin_nontemporal_load(csr + i);
        int s1 = __builtin_nontemporal_load(csr + i + 1);
        acc8(fa, hs[(size_t)s0 * 4 + lane]);
        acc8(fb, hs[(size_t)s1 * 4 + lane]);
    }
    if (i < end) {
        int s0 = __builtin_nontemporal_load(csr + i);
        acc8(fa, hs[(size_t)s0 * 4 + lane]);
    }
    float dn = dinv[node];
    const float4* bb4 = (const float4*)(b2 + lane * 8);
    float4 b0 = bb4[0], b1v = bb4[1];
    float4 o0, o1;
    o0.x = fmaxf((fa[0] + fb[0]) * dn + b0.x, 0.0f);
    o0.y = fmaxf((fa[1] + fb[1]) * dn + b0.y, 0.0f);
    o0.z = fmaxf((fa[2] + fb[2]) * dn + b0.z, 0.0f);
    o0.w = fmaxf((fa[3] + fb[3]) * dn + b0.w, 0.0f);
    o1.x = fmaxf((fa[4] + fb[4]) * dn + b1v.x, 0.0f);
    o1.y = fmaxf((fa[5] + fb[5]) * dn + b1v.y, 0.0f);
    o1.z = fmaxf((fa[6] + fb[6]) * dn + b1v.z, 0.0f);
    o1.w = fmaxf((fa[7] + fb[7]) * dn + b1v.w, 0.0f);
    float4* o = (float4*)(out + (size_t)node * OUTD + lane * 8);
    o[0] = o0;
    o[1] = o1;
}

// ================= launch =================

extern "C" void kernel_launch(void* const* d_in, const int* in_sizes, int n_in,
                              void* d_out, int out_size, void* d_ws, size_t ws_size,
                              hipStream_t stream) {
    const float* x  = (const float*)d_in[0];
    const int*   ei = (const int*)  d_in[1];
    const float* W1 = (const float*)d_in[2];
    const float* b1 = (const float*)d_in[3];
    const float* W2 = (const float*)d_in[4];
    const float* b2 = (const float*)d_in[5];

    const int N = in_sizes[0] / IN_DIM;   // 100000
    const int E = in_sizes[1] / 2;        // 1600000
    const int* srcI = ei;
    const int* dstI = ei + E;
    float* out = (float*)d_out;

    // workspace layout
    float* dinv         = (float*)d_ws;                       // 131072 slot
    int*   rs           = (int*)d_ws + 131072;                // N+1 (131072 slot)
    int*   bucketCnt    = rs + 131072;                        // 256
    int*   bucketBase   = bucketCnt + 256;                    // 256 (NB+1)
    int*   bucketCursor = bucketBase + 256;                   // 256
    int*   ebuf         = bucketCursor + 256;                 // E packed words
    int*   csr          = ebuf + E;                           // E
    uint2* hs1b         = (uint2*)(csr + E);                  // N*16 uint2 (bf16 [N][64]); reused as hs2b (N*8)
    float* agg1         = (float*)(hs1b + (size_t)N * 16);    // N*64 fp32

    hipMemsetAsync(bucketCnt, 0, NB * sizeof(int), stream);
    k_bcount  <<<256, 256, 0, stream>>>(dstI, bucketCnt, E);
    k_bscan   <<<1, 256, 0, stream>>>(bucketCnt, bucketBase, bucketCursor, rs, N, E);
    k_bscatter<<<(E + CHUNK - 1) / CHUNK, 256, 0, stream>>>(srcI, dstI, bucketCursor, ebuf, E);
    k_bfinal  <<<NB, 256, 0, stream>>>(ebuf, bucketBase, rs, dinv, csr, N);

    k_gemm1<<<(N + 31) / 32, 256, 0, stream>>>(x, W1, dinv, hs1b);
    k_agg1 <<<(N * 8 + 255) / 256, 256, 0, stream>>>((const uint4*)hs1b, rs, csr, agg1, N);
    k_gemm2<<<(N + 31) / 32, 256, 0, stream>>>(agg1, W2, b1, dinv, hs1b);   // hs1b reused as hs2b
    k_agg2 <<<(N * 4 + 255) / 256, 256, 0, stream>>>((const uint4*)hs1b, rs, csr, dinv, b2, out, N);
}